// Round 3
// baseline (631.010 us; speedup 1.0000x reference)
//
#include <hip/hip_runtime.h>
#include <math.h>

// Problem constants (match reference)
constexpr int D_ = 64;
constexpr int N_ = 8192;
constexpr int DIM_ = 256;
constexpr int K_ = 32;
constexpr int L_ = 1;
constexpr int P_ = D_ - L_;  // 63
constexpr float TEMP_ = 0.1f;
constexpr float EPS_ = 1e-8f;

constexpr int ROWS_PER_BLOCK = 256;
constexpr int CHUNKS = N_ / ROWS_PER_BLOCK;  // 32
constexpr int BATCH = 16;                    // rows per wave per LDS round
constexpr int LDSTR = 65;                    // stride (words) -> 2-way (free) conflicts

// Fused kernel: streaming sums+norms, then the LAST block of each d runs the
// top-K + sample-normalize epilogue inline (decoupled-lookback style).
//
// Hot loop is barrier-free: the batched transpose-reduce only touches the
// OWN wave's LDS region (w == tid>>6), so within-wave DS ordering suffices.
__global__ __launch_bounds__(256, 4) void k1_fused(const float* __restrict__ emb,
                                                   float* __restrict__ normsq,
                                                   float* __restrict__ sum_all,
                                                   int* __restrict__ done,
                                                   float* __restrict__ nS,
                                                   float* __restrict__ out) {
  const int b = blockIdx.x;
  const int d = b / CHUNKS;
  const int chunk = b % CHUNKS;
  const int tid = threadIdx.x;
  const int wave = tid >> 6;
  const int lane = tid & 63;
  const float* base = emb + (size_t)d * N_ * DIM_;

  __shared__ union {
    float sq[4][BATCH * LDSTR];  // 16.25 KB (hot loop)
    float vals[N_];              // 32 KB (epilogue top-K)
  } u;
  __shared__ int s_last;

  float a0 = 0.f, a1 = 0.f, a2 = 0.f, a3 = 0.f;
  const int wrow0 = chunk * ROWS_PER_BLOCK + wave * 64;

  for (int batch = 0; batch < 64 / BATCH; ++batch) {
    const int r0 = wrow0 + batch * BATCH;
#pragma unroll
    for (int r = 0; r < BATCH; ++r) {
      const float4 v = *reinterpret_cast<const float4*>(base + (size_t)(r0 + r) * DIM_ + (lane << 2));
      a0 += v.x; a1 += v.y; a2 += v.z; a3 += v.w;
      u.sq[wave][r * LDSTR + lane] = v.x * v.x + v.y * v.y + v.z * v.z + v.w * v.w;
    }
    // Within-wave transpose-reduce: 4 threads per row, 16 adds each, 2 shfl.
    // tid>>2 in [16*wave, 16*wave+16) -> reads own wave's buffer only.
    {
      const int rr = tid >> 2;
      const int q = tid & 3;
      const int r = rr & 15;
      const float* p = &u.sq[wave][r * LDSTR + q * 16];
      float s = 0.f;
#pragma unroll
      for (int i = 0; i < 16; ++i) s += p[i];
      s += __shfl_xor(s, 1, 64);
      s += __shfl_xor(s, 2, 64);
      if (q == 0) {
        const int row = chunk * ROWS_PER_BLOCK + wave * 64 + batch * BATCH + r;
        normsq[(size_t)d * N_ + row] = s;
      }
    }
  }

  // Per-dim sums: own-wave LDS write (no barrier), barrier, cross-wave combine.
  reinterpret_cast<float4*>(&u.sq[wave][0])[lane] = make_float4(a0, a1, a2, a3);
  __syncthreads();
  {
    const float s = u.sq[0][tid] + u.sq[1][tid] + u.sq[2][tid] + u.sq[3][tid];
    atomicAdd(&sum_all[d * DIM_ + tid], s);
  }

  // Release our writes, bump the per-d counter; last block runs the epilogue.
  __threadfence();
  if (tid == 0) {
    const int old = atomicAdd(&done[d], 1);
    s_last = (old == CHUNKS - 1);
  }
  __syncthreads();
  if (!s_last) return;
  __threadfence();  // acquire: see all 32 blocks' normsq / sum_all

  // ---------------- epilogue: top-K (stable tie-break) ----------------
  for (int i = tid; i < N_; i += 256) u.vals[i] = normsq[(size_t)d * N_ + i];
  __syncthreads();

  __shared__ unsigned long long wbest[4];
  __shared__ int topidx[K_];
  // key = (float bits)<<32 | (N-1-i): larger norm wins, then lower index
  // (matches stable jnp.argsort(-norms); valid since norms^2 >= 0).
  const int cbase = tid * 32;
  unsigned long long my = 0ull;
  for (int r = 0; r < 32; ++r) {
    const int i = cbase + r;
    const unsigned long long key =
        ((unsigned long long)__float_as_uint(u.vals[i]) << 32) | (unsigned)(N_ - 1 - i);
    if (key > my) my = key;
  }
  for (int k = 0; k < K_; ++k) {
    unsigned long long bw = my;
#pragma unroll
    for (int off = 1; off < 64; off <<= 1) {
      const unsigned long long o = __shfl_xor(bw, off, 64);
      if (o > bw) bw = o;
    }
    if (lane == 0) wbest[wave] = bw;
    __syncthreads();
    unsigned long long bb = wbest[0];
    for (int w = 1; w < 4; ++w)
      if (wbest[w] > bb) bb = wbest[w];
    const int idx = N_ - 1 - (int)(bb & 0xFFFFFFFFu);
    if (tid == 0) topidx[k] = idx;
    if ((idx >> 5) == tid) {  // owner removes + rescans its 32-element chunk
      u.vals[idx] = 0.0f;
      my = 0ull;
      for (int r = 0; r < 32; ++r) {
        const int i = cbase + r;
        const unsigned long long key =
            ((unsigned long long)__float_as_uint(u.vals[i]) << 32) | (unsigned)(N_ - 1 - i);
        if (key > my) my = key;
      }
    }
    __syncthreads();
  }

  // ---------------- epilogue: samples + normalize ----------------
  float ts = 0.f;
#pragma unroll 4
  for (int k = 0; k < K_; ++k) {
    ts += base[(size_t)topidx[k] * DIM_ + tid];
  }
  const float s1 = sum_all[d * DIM_ + tid];
  const float s2 = s1 - ts;

  float q1 = s1 * s1, q2 = s2 * s2;
#pragma unroll
  for (int off = 32; off > 0; off >>= 1) {
    q1 += __shfl_down(q1, off, 64);
    q2 += __shfl_down(q2, off, 64);
  }
  __shared__ float w1[4], w2[4];
  __shared__ float inv1s, inv2s;
  if (lane == 0) { w1[wave] = q1; w2[wave] = q2; }
  __syncthreads();
  if (tid == 0) {
    const float n1 = sqrtf(w1[0] + w1[1] + w1[2] + w1[3]);
    const float n2 = sqrtf(w2[0] + w2[1] + w2[2] + w2[3]);
    inv1s = 1.0f / fmaxf(n1, EPS_);
    inv2s = 1.0f / fmaxf(n2, EPS_);
    if (d == 0) out[0] = 0.0f;  // zero the loss accumulator before k4
  }
  __syncthreads();
  nS[d * DIM_ + tid] = s1 * inv1s;
  nS[(D_ + d) * DIM_ + tid] = s2 * inv2s;
}

// Loss kernel: 4 waves per pair; wave w handles negatives [8w, 8w+8) for both
// sides with an online (max, sumexp) held redundantly in all lanes (uniform),
// combined across waves + pos term via LDS.
__global__ __launch_bounds__(256) void k4_loss(const float* __restrict__ nS,
                                               const int* __restrict__ negidx,
                                               float* __restrict__ out) {
  const int p = blockIdx.x;
  const int tid = threadIdx.x;
  const int wave = tid >> 6;
  const int lane = tid & 63;

  const float4 vi = *reinterpret_cast<const float4*>(nS + p * DIM_ + (lane << 2));
  const float4 vj = *reinterpret_cast<const float4*>(nS + (p + L_) * DIM_ + (lane << 2));

  float dp = vi.x * vj.x + vi.y * vj.y + vi.z * vj.z + vi.w * vj.w;
#pragma unroll
  for (int off = 1; off < 64; off <<= 1) dp += __shfl_xor(dp, off, 64);
  const float invT = 1.0f / TEMP_;
  const float posT = dp * invT;

  float mi = -INFINITY, si = 0.f, mj = -INFINITY, sj = 0.f;
#pragma unroll
  for (int kk = 0; kk < K_ / 4; ++kk) {
    const int k = wave * (K_ / 4) + kk;
    const int idx = negidx[p * K_ + k];
    const float4 vn = *reinterpret_cast<const float4*>(nS + idx * DIM_ + (lane << 2));
    float di = vi.x * vn.x + vi.y * vn.y + vi.z * vn.z + vi.w * vn.w;
    float dj = vj.x * vn.x + vj.y * vn.y + vj.z * vn.z + vj.w * vn.w;
#pragma unroll
    for (int off = 1; off < 64; off <<= 1) {
      di += __shfl_xor(di, off, 64);
      dj += __shfl_xor(dj, off, 64);
    }
    const float li = di * invT;
    const float lj = dj * invT;
    if (li > mi) { si = si * expf(mi - li) + 1.f; mi = li; } else { si += expf(li - mi); }
    if (lj > mj) { sj = sj * expf(mj - lj) + 1.f; mj = lj; } else { sj += expf(lj - mj); }
  }

  __shared__ float pm[2][4], ps[2][4];
  if (lane == 0) {
    pm[0][wave] = mi; ps[0][wave] = si;
    pm[1][wave] = mj; ps[1][wave] = sj;
  }
  __syncthreads();
  if (tid == 0) {
    float total = 0.f;
#pragma unroll
    for (int side = 0; side < 2; ++side) {
      float m = posT;
      for (int w = 0; w < 4; ++w) m = fmaxf(m, pm[side][w]);
      float s = expf(posT - m);
      for (int w = 0; w < 4; ++w) s += ps[side][w] * expf(pm[side][w] - m);
      total += m + logf(s) - posT;  // lse - posT
    }
    atomicAdd(out, total / (2.0f * P_));
  }
}

extern "C" void kernel_launch(void* const* d_in, const int* in_sizes, int n_in,
                              void* d_out, int out_size, void* d_ws, size_t ws_size,
                              hipStream_t stream) {
  const float* emb = (const float*)d_in[0];
  const int* negidx = (const int*)d_in[1];
  float* out = (float*)d_out;

  // Workspace layout (floats):
  float* normsq = (float*)d_ws;                 // D*N = 524288
  float* sum_all = normsq + (size_t)D_ * N_;    // D*DIM = 16384
  int* done = (int*)(sum_all + D_ * DIM_);      // D = 64 ints
  float* nS = (float*)(done + D_);              // 2*D*DIM = 32768

  // Zero accumulators + completion flags in one small memset.
  hipMemsetAsync(sum_all, 0, (D_ * DIM_ + D_) * sizeof(float), stream);

  k1_fused<<<D_ * CHUNKS, 256, 0, stream>>>(emb, normsq, sum_all, done, nS, out);
  k4_loss<<<P_, 256, 0, stream>>>(nS, negidx, out);
}

// Round 4
// 150.711 us; speedup vs baseline: 4.1869x; 4.1869x over previous
//
#include <hip/hip_runtime.h>
#include <math.h>

// Problem constants (match reference)
constexpr int D_ = 64;
constexpr int N_ = 8192;
constexpr int DIM_ = 256;
constexpr int K_ = 32;
constexpr int L_ = 1;
constexpr int P_ = D_ - L_;  // 63
constexpr float TEMP_ = 0.1f;
constexpr float EPS_ = 1e-8f;

constexpr int ROWS_PER_BLOCK = 256;
constexpr int CHUNKS = N_ / ROWS_PER_BLOCK;  // 32
constexpr int BATCH = 16;                    // rows per wave per LDS round
constexpr int LDSTR = 65;                    // stride (words) -> 2-way (free) conflicts

// Kernel 1: pure streaming pass (no fences, no cross-block coherence games —
// kernel boundary provides device-wide visibility for free).
// Hot loop is barrier-free: the batched transpose-reduce only touches the
// OWN wave's LDS region, so within-wave DS ordering suffices (verified r3).
__global__ __launch_bounds__(256, 4) void k1_sums_norms(const float* __restrict__ emb,
                                                        float* __restrict__ normsq,
                                                        float* __restrict__ sum_all) {
  const int b = blockIdx.x;
  const int d = b / CHUNKS;
  const int chunk = b % CHUNKS;
  const int tid = threadIdx.x;
  const int wave = tid >> 6;
  const int lane = tid & 63;
  const float* base = emb + (size_t)d * N_ * DIM_;

  __shared__ __align__(16) float sq[4][BATCH * LDSTR];  // 16.25 KB

  float a0 = 0.f, a1 = 0.f, a2 = 0.f, a3 = 0.f;
  const int wrow0 = chunk * ROWS_PER_BLOCK + wave * 64;

  for (int batch = 0; batch < 64 / BATCH; ++batch) {
    const int r0 = wrow0 + batch * BATCH;
#pragma unroll
    for (int r = 0; r < BATCH; ++r) {
      const float4 v = *reinterpret_cast<const float4*>(base + (size_t)(r0 + r) * DIM_ + (lane << 2));
      a0 += v.x; a1 += v.y; a2 += v.z; a3 += v.w;
      sq[wave][r * LDSTR + lane] = v.x * v.x + v.y * v.y + v.z * v.z + v.w * v.w;
    }
    // Within-wave transpose-reduce: 4 threads/row, 16 adds each, 2 shfl.
    {
      const int rr = tid >> 2;
      const int q = tid & 3;
      const int r = rr & 15;
      const float* p = &sq[wave][r * LDSTR + q * 16];
      float s = 0.f;
#pragma unroll
      for (int i = 0; i < 16; ++i) s += p[i];
      s += __shfl_xor(s, 1, 64);
      s += __shfl_xor(s, 2, 64);
      if (q == 0) {
        const int row = chunk * ROWS_PER_BLOCK + wave * 64 + batch * BATCH + r;
        normsq[(size_t)d * N_ + row] = s;
      }
    }
  }

  // Per-dim sums: own-wave LDS stash, one barrier, cross-wave combine.
  reinterpret_cast<float4*>(&sq[wave][0])[lane] = make_float4(a0, a1, a2, a3);
  __syncthreads();
  const float s = sq[0][tid] + sq[1][tid] + sq[2][tid] + sq[3][tid];
  atomicAdd(&sum_all[d * DIM_ + tid], s);
}

// Kernel 2+3 fused: one block per d. Top-K by norm^2 (stable lowest-index
// tie-break, matching jnp.argsort(-norms)), then gather + samples + normalize.
// Strided element ownership (i = tid + 256*r) -> conflict-free LDS banks.
__global__ __launch_bounds__(256) void k23_topk_samples(const float* __restrict__ emb,
                                                        const float* __restrict__ normsq,
                                                        const float* __restrict__ sum_all,
                                                        float* __restrict__ nS,
                                                        float* __restrict__ out) {
  const int d = blockIdx.x;
  const int tid = threadIdx.x;
  const int lane = tid & 63;
  const int wave = tid >> 6;

  __shared__ float vals[N_];  // 32 KB
  __shared__ unsigned long long wbest[4];
  __shared__ int topidx[K_];

  for (int i = tid; i < N_; i += 256) vals[i] = normsq[(size_t)d * N_ + i];
  __syncthreads();

  // key = (float bits)<<32 | (N-1-i): larger norm wins, then lower index
  // (valid: norms^2 >= 0 so the float bit pattern is order-preserving).
  unsigned long long my = 0ull;
#pragma unroll 8
  for (int r = 0; r < 32; ++r) {
    const int i = tid + (r << 8);
    const unsigned long long key =
        ((unsigned long long)__float_as_uint(vals[i]) << 32) | (unsigned)(N_ - 1 - i);
    if (key > my) my = key;
  }

  for (int k = 0; k < K_; ++k) {
    unsigned long long bw = my;
#pragma unroll
    for (int off = 1; off < 64; off <<= 1) {
      const unsigned long long o = __shfl_xor(bw, off, 64);
      if (o > bw) bw = o;
    }
    if (lane == 0) wbest[wave] = bw;
    __syncthreads();
    unsigned long long bb = wbest[0];
    for (int w = 1; w < 4; ++w)
      if (wbest[w] > bb) bb = wbest[w];
    const int idx = N_ - 1 - (int)(bb & 0xFFFFFFFFu);
    if (tid == 0) topidx[k] = idx;
    if ((idx & 255) == tid) {  // owner removes + rescans its strided chunk
      vals[idx] = 0.0f;
      my = 0ull;
      for (int r = 0; r < 32; ++r) {
        const int i = tid + (r << 8);
        const unsigned long long key =
            ((unsigned long long)__float_as_uint(vals[i]) << 32) | (unsigned)(N_ - 1 - i);
        if (key > my) my = key;
      }
    }
    __syncthreads();
  }

  // ---- samples + normalize ----
  const float* base = emb + (size_t)d * N_ * DIM_;
  float ts = 0.f;
#pragma unroll 4
  for (int k = 0; k < K_; ++k) {
    ts += base[(size_t)topidx[k] * DIM_ + tid];
  }
  const float s1 = sum_all[d * DIM_ + tid];
  const float s2 = s1 - ts;

  float q1 = s1 * s1, q2 = s2 * s2;
#pragma unroll
  for (int off = 32; off > 0; off >>= 1) {
    q1 += __shfl_down(q1, off, 64);
    q2 += __shfl_down(q2, off, 64);
  }
  __shared__ float w1[4], w2[4];
  __shared__ float inv1s, inv2s;
  if (lane == 0) { w1[wave] = q1; w2[wave] = q2; }
  __syncthreads();
  if (tid == 0) {
    const float n1 = sqrtf(w1[0] + w1[1] + w1[2] + w1[3]);
    const float n2 = sqrtf(w2[0] + w2[1] + w2[2] + w2[3]);
    inv1s = 1.0f / fmaxf(n1, EPS_);
    inv2s = 1.0f / fmaxf(n2, EPS_);
    if (d == 0) out[0] = 0.0f;  // zero loss accumulator (ordered before k4)
  }
  __syncthreads();
  nS[d * DIM_ + tid] = s1 * inv1s;
  nS[(D_ + d) * DIM_ + tid] = s2 * inv2s;
}

// Loss kernel: 4 waves per pair; wave w handles 8 negatives for both sides
// with an online (max, sumexp) held uniformly in all lanes, combined via LDS.
__global__ __launch_bounds__(256) void k4_loss(const float* __restrict__ nS,
                                               const int* __restrict__ negidx,
                                               float* __restrict__ out) {
  const int p = blockIdx.x;
  const int tid = threadIdx.x;
  const int wave = tid >> 6;
  const int lane = tid & 63;

  const float4 vi = *reinterpret_cast<const float4*>(nS + p * DIM_ + (lane << 2));
  const float4 vj = *reinterpret_cast<const float4*>(nS + (p + L_) * DIM_ + (lane << 2));

  float dp = vi.x * vj.x + vi.y * vj.y + vi.z * vj.z + vi.w * vj.w;
#pragma unroll
  for (int off = 1; off < 64; off <<= 1) dp += __shfl_xor(dp, off, 64);
  const float invT = 1.0f / TEMP_;
  const float posT = dp * invT;

  float mi = -INFINITY, si = 0.f, mj = -INFINITY, sj = 0.f;
#pragma unroll
  for (int kk = 0; kk < K_ / 4; ++kk) {
    const int k = wave * (K_ / 4) + kk;
    const int idx = negidx[p * K_ + k];
    const float4 vn = *reinterpret_cast<const float4*>(nS + idx * DIM_ + (lane << 2));
    float di = vi.x * vn.x + vi.y * vn.y + vi.z * vn.z + vi.w * vn.w;
    float dj = vj.x * vn.x + vj.y * vn.y + vj.z * vn.z + vj.w * vn.w;
#pragma unroll
    for (int off = 1; off < 64; off <<= 1) {
      di += __shfl_xor(di, off, 64);
      dj += __shfl_xor(dj, off, 64);
    }
    const float li = di * invT;
    const float lj = dj * invT;
    if (li > mi) { si = si * expf(mi - li) + 1.f; mi = li; } else { si += expf(li - mi); }
    if (lj > mj) { sj = sj * expf(mj - lj) + 1.f; mj = lj; } else { sj += expf(lj - mj); }
  }

  __shared__ float pm[2][4], ps[2][4];
  if (lane == 0) {
    pm[0][wave] = mi; ps[0][wave] = si;
    pm[1][wave] = mj; ps[1][wave] = sj;
  }
  __syncthreads();
  if (tid == 0) {
    float total = 0.f;
#pragma unroll
    for (int side = 0; side < 2; ++side) {
      float m = posT;
      for (int w = 0; w < 4; ++w) m = fmaxf(m, pm[side][w]);
      float s = expf(posT - m);
      for (int w = 0; w < 4; ++w) s += ps[side][w] * expf(pm[side][w] - m);
      total += m + logf(s) - posT;  // lse - posT
    }
    atomicAdd(out, total / (2.0f * P_));
  }
}

extern "C" void kernel_launch(void* const* d_in, const int* in_sizes, int n_in,
                              void* d_out, int out_size, void* d_ws, size_t ws_size,
                              hipStream_t stream) {
  const float* emb = (const float*)d_in[0];
  const int* negidx = (const int*)d_in[1];
  float* out = (float*)d_out;

  // Workspace layout (floats):
  float* normsq = (float*)d_ws;                 // D*N = 524288
  float* sum_all = normsq + (size_t)D_ * N_;    // D*DIM = 16384
  float* nS = sum_all + D_ * DIM_;              // 2*D*DIM = 32768

  hipMemsetAsync(sum_all, 0, D_ * DIM_ * sizeof(float), stream);

  k1_sums_norms<<<D_ * CHUNKS, 256, 0, stream>>>(emb, normsq, sum_all);
  k23_topk_samples<<<D_, 256, 0, stream>>>(emb, normsq, sum_all, nS, out);
  k4_loss<<<P_, 256, 0, stream>>>(nS, negidx, out);
}